// Round 3
// baseline (74.241 us; speedup 1.0000x reference)
//
#include <hip/hip_runtime.h>

#define CCH 3
#define KK 16
#define HW (1024 * 1024)

typedef float vf4 __attribute__((ext_vector_type(4)));

// One vf4 (4 pixels) per thread. Channels processed sequentially
// (#pragma unroll 1) so live param state stays at ~32 SGPRs; K fully
// unrolled. No local arrays -> no scratch, low VGPR pressure.
__global__ __launch_bounds__(256) void pixelwise_kernel(
    const float* __restrict__ x,
    const float* __restrict__ M,
    const float* __restrict__ p_a,
    const float* __restrict__ p_t,
    const float* __restrict__ bias_c,
    const float* __restrict__ bias,
    float* __restrict__ out)
{
    const int base = (blockIdx.x * 256 + threadIdx.x) * 4;

    const float b0 = bias[0];
    float a0 = b0, a1 = b0, a2 = b0, a3 = b0;

#pragma unroll 1
    for (int c = 0; c < CCH; ++c) {
        // wave-uniform scalar params for this channel
        const float rsc = M[c * 3 + 0] + M[c * 3 + 1] + M[c * 3 + 2];
        const float bc  = bias_c[c];
        const float* __restrict__ paP = p_a + c * KK;
        const float* __restrict__ ptP = p_t + c * KK;

        const vf4 xv =
            __builtin_nontemporal_load((const vf4*)(x + c * HW + base));

        const float s0 = fmaf(xv.x, rsc, bc);
        const float s1 = fmaf(xv.y, rsc, bc);
        const float s2 = fmaf(xv.z, rsc, bc);
        const float s3 = fmaf(xv.w, rsc, bc);

#pragma unroll
        for (int k = 0; k < KK; ++k) {
            const float t  = ptP[k];   // uniform -> SGPR
            const float pa = paP[k];   // uniform -> SGPR
            a0 = fmaf(pa, fmaxf(s0 - t, 0.0f), a0);
            a1 = fmaf(pa, fmaxf(s1 - t, 0.0f), a1);
            a2 = fmaf(pa, fmaxf(s2 - t, 0.0f), a2);
            a3 = fmaf(pa, fmaxf(s3 - t, 0.0f), a3);
        }
    }

    vf4 ov;
    ov.x = a0; ov.y = a1; ov.z = a2; ov.w = a3;
    __builtin_nontemporal_store(ov, (vf4*)(out + base));
}

extern "C" void kernel_launch(void* const* d_in, const int* in_sizes, int n_in,
                              void* d_out, int out_size, void* d_ws, size_t ws_size,
                              hipStream_t stream)
{
    const float* x      = (const float*)d_in[0];
    const float* M      = (const float*)d_in[1];
    const float* p_a    = (const float*)d_in[2];
    const float* p_t    = (const float*)d_in[3];
    const float* bias_c = (const float*)d_in[4];
    const float* bias   = (const float*)d_in[5];
    float* out = (float*)d_out;

    const int threads = 256;
    const int blocks  = (HW / 4) / threads;  // 1024 blocks, 16 waves/CU
    pixelwise_kernel<<<blocks, threads, 0, stream>>>(x, M, p_a, p_t, bias_c, bias, out);
}